// Round 3
// baseline (236.624 us; speedup 1.0000x reference)
//
#include <hip/hip_runtime.h>
#include <math.h>

// DCT2net, R8: two kernels, lane = (col, kj) coordinate, barrier-free k2.
//
// R8 changes vs R7 (theory: k2 busy-cycle diet; trans ops were 30% of busy):
//  - shrink via squaring chain again: 1 trans/coeff (rcp) instead of 3
//    (log+exp+rcp). pnz accumulated as sum of r (pnz = 13 - sum r): -1 mul/coeff.
//  - steady loop unrolled x13 with compile-time ring rotation -> all ~37
//    ring-shift movs/step gone. SEGH=39 (3x13), NSEG=13: 9% less total work.
//  - unconditional x loads (all 64 lanes, dup cols coalesce) -> no exec-mask
//    dance; c1col=0 for idle lanes jj>=13 -> nz=0 automatically, no cndmask.
//  - block=64 (single wave), no __syncthreads anywhere in k2.
//  - incremental uniform store pointers (SALU) instead of per-step re-derive.
//  - k3: halo loads issued up-front; halo build shared across block (48 thr of
//    wave 0 + one barrier) instead of a masked full second pass per wave.
//
// K2: per lane-group of 16 (13 kj used), one patch column. Streams image rows:
//   hDCT (x via ds_bpermute) -> 13-reg ring Rv -> vDCT+shrink -> tn, pnz
//   -> w via 4-step DPP row_ror butterfly -> weighted vertical fold ring Hr
//   -> vertical w box-sum ring -> retire H row + vs.
// K3: U[c][dy] = sum_j c1[dy][j] H[a][c][j]; out = diag-sum / col-sum of vs.
//
// ws layout: Hg = 2*488*512*16 f32 (31.98 MB), Wg = 2*512*512 f32 (2 MB).

#define P13    13
#define IMGW   512
#define OUTW   488
#define SEGH   39      // 3x13: steady loop fully unrolled by 13
#define NSEG   13      // 12*39 + 20 = 488
#define HCOLS  512
#define HPITCH 16

struct C1mat { float v[P13 * P13]; };

// ---- compile-time DCT table (identical to host-side double math) ----
constexpr double kPI = 3.14159265358979323846264338327950288;

constexpr double ccos_pm_pi(double th) {
    double term = 1.0, s = 1.0;
    const double th2 = th * th;
    for (int n = 1; n <= 25; ++n) {
        term *= -th2 / (double)((2 * n - 1) * (2 * n));
        s += term;
    }
    return s;
}
constexpr double csqrt(double v) {
    double x = (v > 1.0) ? v : 1.0;
    for (int i = 0; i < 64; ++i) x = 0.5 * (x + v / x);
    return x;
}
constexpr C1mat make_c1() {
    C1mat m{};
    const double s213 = csqrt(2.0 / 13.0);
    const double is2  = 1.0 / csqrt(2.0);
    for (int x = 0; x < P13; ++x)
        for (int k = 0; k < P13; ++k) {
            int mm = ((2 * x + 1) * k) % 52;
            double th = (mm <= 26) ? (mm * kPI / 26.0) : ((mm - 52) * kPI / 26.0);
            double Ci = (k == 0) ? is2 : 1.0;
            m.v[x * P13 + k] = (float)(s213 * Ci * ccos_pm_pi(th));
        }
    return m;
}
__device__ constexpr C1mat c1c = make_c1();

struct FalseT { static constexpr bool value = false; };
struct TrueT  { static constexpr bool value = true; };

// rotate-reduce add within each 16-lane DPP row: N in {1,2,4,8}
#define ROR16_ADD(v, N)                                                        \
    v += __int_as_float(__builtin_amdgcn_mov_dpp(__float_as_int(v),            \
                                                 0x120 + (N), 0xF, 0xF, true))

// vDCT + shrink. Rv read with ring rotation RO (logical y -> Rv[(y+RO)%13]).
// pnzr accumulates r = 1/(1+u^64); nz = 1-r, so caller uses pnz = 13 - pnzr.
// Idle lanes (t==0): p64=0 -> r=rcp(1)=1 exactly -> nz=0, tn=0.
template<int RO>
__device__ __forceinline__ void vdct_shrink_r(const float (&Rv)[P13], float i2sq,
                                              float (&tn)[P13], float& pnzr)
{
    float Se[6], So[6];
#pragma unroll
    for (int k = 0; k < 6; ++k) {
        float a = Rv[(k + RO) % P13], b = Rv[(12 - k + RO) % P13];
        Se[k] = a + b; So[k] = a - b;
    }
    const float R6v = Rv[(6 + RO) % P13];
#pragma unroll
    for (int i = 0; i < P13; ++i) {
        float t;
        if ((i & 1) == 0) {
            t = c1c.v[6 * P13 + i] * R6v;
#pragma unroll
            for (int k = 0; k < 6; ++k) t = fmaf(c1c.v[k * P13 + i], Se[k], t);
        } else {
            t = c1c.v[0 * P13 + i] * So[0];
#pragma unroll
            for (int k = 1; k < 6; ++k) t = fmaf(c1c.v[k * P13 + i], So[k], t);
        }
        // p2 = min((t*inv3s)^2, 1.3^2): clamp == med3(u,-1.3,1.3) squared.
        float p2 = fminf(t * t * i2sq, 1.69f);
        float p4 = p2 * p2, p8 = p4 * p4, p16 = p8 * p8, p32 = p16 * p16, p64 = p32 * p32;
        float r  = __builtin_amdgcn_rcpf(p64 + 1.0f);
        pnzr += r;
        tn[i] = fmaf(-t, r, t);      // t*nz with nz = 1-r
    }
}

// weighted vertical inverse fold; H slots rotated by R (logical d -> (d+R)%13)
template<int R>
__device__ __forceinline__ void fold_vert_r(const float (&tn)[P13], float w1,
                                            float (&H)[P13])
{
#pragma unroll
    for (int dx = 0; dx < 6; ++dx) {
        float E = c1c.v[dx * P13 + 0] * tn[0];
#pragma unroll
        for (int i = 2; i < P13; i += 2) E = fmaf(c1c.v[dx * P13 + i], tn[i], E);
        float O = c1c.v[dx * P13 + 1] * tn[1];
#pragma unroll
        for (int i = 3; i < P13; i += 2) O = fmaf(c1c.v[dx * P13 + i], tn[i], O);
        H[(dx + R) % P13]      = fmaf(w1, E + O, H[(dx + R) % P13]);
        H[(12 - dx + R) % P13] = fmaf(w1, E - O, H[(12 - dx + R) % P13]);
    }
    float z6 = c1c.v[6 * P13 + 0] * tn[0];
#pragma unroll
    for (int i = 2; i < P13; i += 2) z6 = fmaf(c1c.v[6 * P13 + i], tn[i], z6);
    H[(6 + R) % P13] = fmaf(w1, z6, H[(6 + R) % P13]);
}

// one steady-state streaming step at compile-time ring phase R.
// Entry state: rings at rotation R (phase r of the 13-unroll). Always retires.
template<int R>
__device__ __forceinline__ void k2_sub(
    float (&Rv)[P13], float (&Hr)[P13], float (&wr)[P13],
    float& vs, float& xv, const float*& xp, const float* xlast, int xcol,
    const float (&c1col)[P13], int g, int jj, float i2sq,
    float*& Hp, float*& Wp, int voH, int voW)
{
    float xw[P13];
#pragma unroll
    for (int y = 0; y < P13; ++y)
        xw[y] = __int_as_float(
            __builtin_amdgcn_ds_bpermute(4 * (g + y), __float_as_int(xv)));
    {   // prefetch next image row (row ptr clamped at 511)
        const float* xq = (xp < xlast) ? xp : xlast;
        xv = xq[xcol]; xp += IMGW;
    }
    float a0 = c1col[0] * xw[0], a1 = c1col[1] * xw[1];
#pragma unroll
    for (int y = 2; y < P13; y += 2) a0 = fmaf(c1col[y], xw[y], a0);
#pragma unroll
    for (int y = 3; y < P13; y += 2) a1 = fmaf(c1col[y], xw[y], a1);
    Rv[R] = a0 + a1;                 // overwrite oldest; reads use rot R+1

    float tn[P13]; float pnzr = 0.0f;
    vdct_shrink_r<(R + 1) % P13>(Rv, i2sq, tn, pnzr);
    float pnz = 13.0f - pnzr;        // idle lanes: 13 - 13 = 0
    ROR16_ADD(pnz, 1); ROR16_ADD(pnz, 2); ROR16_ADD(pnz, 4); ROR16_ADD(pnz, 8);
    const float w = __builtin_amdgcn_rcpf(1.0f + pnz);
    vs += w;
    fold_vert_r<R>(tn, w, Hr);
    wr[R] = w;                       // overwrite w from 13 steps ago
    // retire H row a and vertical w-sum
    Hp[voH] = Hr[R];
    Hp += HCOLS * HPITCH;
    if (jj == 0) Wp[voW] = vs;
    Wp += IMGW;
    vs -= wr[(R + 1) % P13];         // drop w(a)
    Hr[R] = 0.0f;                    // fresh accumulator (logical 12 next step)
}

__global__ __launch_bounds__(64) void dct2net_k2(
    const float* __restrict__ xg, const float* __restrict__ sigmag,
    float* __restrict__ Hg, float* __restrict__ Wg)
{
    __shared__ float c1lds[169];
    const int tid = threadIdx.x;
    c1lds[tid] = c1c.v[tid];
    c1lds[tid + 64] = c1c.v[tid + 64];
    if (tid < 41) c1lds[tid + 128] = c1c.v[tid + 128];
    // single-wave block: ds write->read in program order, no barrier needed

    const int lane = tid;
    const int g    = lane >> 4;            // col group 0..3
    const int jj   = lane & 15;            // kj (0..12 used)
    const int img  = blockIdx.z;
    const int hs   = blockIdx.y * SEGH;
    const int segrows = (OUTW - hs < SEGH) ? (OUTW - hs) : SEGH;
    const int cbw  = blockIdx.x * 4;       // wave's first col
    const int col  = cbw + g;

    const float inv3s = 1.0f / (3.0f * sigmag[0]);
    const float i2sq  = inv3s * inv3s;
    const float* xin  = xg + (size_t)img * IMGW * IMGW;

    float c1col[P13];
#pragma unroll
    for (int y = 0; y < P13; ++y)
        c1col[y] = (jj < 13) ? c1lds[y * P13 + jj] : 0.0f;  // 0 => nz=0 for idle

    float Rv[P13], Hr[P13], wr[P13];
#pragma unroll
    for (int k = 0; k < P13; ++k) { Rv[k] = 0.0f; Hr[k] = 0.0f; wr[k] = 0.0f; }
    float vs = 0.0f;

    int xcol = cbw + (lane & 15); xcol = (xcol < IMGW - 1) ? xcol : (IMGW - 1);
    const float* xp    = xin + (size_t)hs * IMGW;
    const float* xlast = xin + (size_t)(IMGW - 1) * IMGW;
    float xv = xp[xcol];                   // all 64 lanes: dup cols coalesce
    xp += IMGW;

    float* Hp = Hg + ((size_t)img * OUTW + hs) * HCOLS * HPITCH;
    float* Wp = Wg + ((size_t)img * IMGW + hs) * IMGW;
    const int voH = col * HPITCH + jj;
    const int voW = col;

    // shifting variant (identity rotation) for ramp and tail
    auto stepS = [&](auto SH, auto RT) {
        float xw[P13];
#pragma unroll
        for (int y = 0; y < P13; ++y)
            xw[y] = __int_as_float(
                __builtin_amdgcn_ds_bpermute(4 * (g + y), __float_as_int(xv)));
        { const float* xq = (xp < xlast) ? xp : xlast; xv = xq[xcol]; xp += IMGW; }
        float a0 = c1col[0] * xw[0], a1 = c1col[1] * xw[1];
#pragma unroll
        for (int y = 2; y < P13; y += 2) a0 = fmaf(c1col[y], xw[y], a0);
#pragma unroll
        for (int y = 3; y < P13; y += 2) a1 = fmaf(c1col[y], xw[y], a1);
#pragma unroll
        for (int q = 0; q < P13 - 1; ++q) Rv[q] = Rv[q + 1];
        Rv[P13 - 1] = a0 + a1;

        if constexpr (decltype(SH)::value) {
            float tn[P13]; float pnzr = 0.0f;
            vdct_shrink_r<0>(Rv, i2sq, tn, pnzr);
            float pnz = 13.0f - pnzr;
            ROR16_ADD(pnz, 1); ROR16_ADD(pnz, 2); ROR16_ADD(pnz, 4); ROR16_ADD(pnz, 8);
            const float w = __builtin_amdgcn_rcpf(1.0f + pnz);
            vs += w;
            fold_vert_r<0>(tn, w, Hr);
#pragma unroll
            for (int q = 0; q < P13 - 1; ++q) wr[q] = wr[q + 1];
            wr[P13 - 1] = w;
            if constexpr (decltype(RT)::value) {
                Hp[voH] = Hr[0];
                Hp += HCOLS * HPITCH;
                if (jj == 0) Wp[voW] = vs;
                Wp += IMGW;
                vs -= wr[0];               // w(a) after shift
            }
#pragma unroll
            for (int q = 0; q < P13 - 1; ++q) Hr[q] = Hr[q + 1];
            Hr[P13 - 1] = 0.0f;
        }
    };

#pragma unroll 1
    for (int k = 0; k < 12; ++k) stepS(FalseT{}, FalseT{});   // fill Rv
#pragma unroll 1
    for (int k = 0; k < 12; ++k) stepS(TrueT{}, FalseT{});    // fill Hr/wr

#define SUB(R) k2_sub<R>(Rv, Hr, wr, vs, xv, xp, xlast, xcol, c1col, g, jj, \
                         i2sq, Hp, Wp, voH, voW)
    int kleft = segrows;
#pragma unroll 1
    while (kleft >= 13) {
        SUB(0); SUB(1); SUB(2); SUB(3); SUB(4); SUB(5); SUB(6);
        SUB(7); SUB(8); SUB(9); SUB(10); SUB(11); SUB(12);
        kleft -= 13;
    }
#undef SUB
#pragma unroll 1
    for (; kleft > 0; --kleft) stepS(TrueT{}, TrueT{});       // tail (rot = 0)
}

__global__ __launch_bounds__(256) void dct2net_k3(
    const float* __restrict__ Hg, const float* __restrict__ Wg,
    float* __restrict__ outg)
{
    __shared__ float U[4][76][14];   // stride 14: 2-way bank alias only (free)
    __shared__ float vw[4][80];
    const int tid  = threadIdx.x;
    const int lane = tid & 63;
    const int wv   = tid >> 6;
    const int img  = blockIdx.z;
    const int a0   = blockIdx.y * 4;
    const int a    = a0 + wv;               // out row (<= 487)
    const int cb   = blockIdx.x * 64;       // out col base

    // ---- issue all loads up front (main + halo) ----
    int c = cb + lane; c = (c < 499) ? c : 499;
    const float* hp = &Hg[(((size_t)img * OUTW + a) * HCOLS + c) * HPITCH];
    float4 m0 = *(const float4*)hp;
    float4 m1 = *(const float4*)(hp + 4);
    float4 m2 = *(const float4*)(hp + 8);
    float  m3 = hp[12];
    float  wm = Wg[((size_t)img * IMGW + a) * IMGW + c];

    const bool halo = (tid < 48);           // wave 0 only: 4 rows x 12 halo cols
    const int  hr = tid / 12;
    const int  hm = tid - hr * 12;
    float4 s0 = {0,0,0,0}, s1 = {0,0,0,0}, s2 = {0,0,0,0};
    float  s3 = 0.0f, ws = 0.0f;
    if (halo) {
        const int ah = a0 + hr;
        int c2 = cb + 64 + hm; c2 = (c2 < 499) ? c2 : 499;
        const float* hq = &Hg[(((size_t)img * OUTW + ah) * HCOLS + c2) * HPITCH];
        s0 = *(const float4*)hq;
        s1 = *(const float4*)(hq + 4);
        s2 = *(const float4*)(hq + 8);
        s3 = hq[12];
        ws = Wg[((size_t)img * IMGW + ah) * IMGW + c2];
    }

    // ---- main build: U[wv][lane][*], vw[wv][lane] ----
    {
        float hv[P13] = {m0.x,m0.y,m0.z,m0.w, m1.x,m1.y,m1.z,m1.w,
                         m2.x,m2.y,m2.z,m2.w, m3};
#pragma unroll
        for (int dy = 0; dy < P13; ++dy) {
            float u0 = c1c.v[dy * P13 + 0] * hv[0];
            float u1 = c1c.v[dy * P13 + 1] * hv[1];
#pragma unroll
            for (int j = 2; j < P13; j += 2) u0 = fmaf(c1c.v[dy * P13 + j], hv[j], u0);
#pragma unroll
            for (int j = 3; j < P13; j += 2) u1 = fmaf(c1c.v[dy * P13 + j], hv[j], u1);
            U[wv][lane][dy] = u0 + u1;
        }
        vw[wv][lane] = wm;
    }
    // ---- halo build (wave 0 lanes 0..47 cover all 4 rows) ----
    if (halo) {
        float hv[P13] = {s0.x,s0.y,s0.z,s0.w, s1.x,s1.y,s1.z,s1.w,
                         s2.x,s2.y,s2.z,s2.w, s3};
#pragma unroll
        for (int dy = 0; dy < P13; ++dy) {
            float u0 = c1c.v[dy * P13 + 0] * hv[0];
            float u1 = c1c.v[dy * P13 + 1] * hv[1];
#pragma unroll
            for (int j = 2; j < P13; j += 2) u0 = fmaf(c1c.v[dy * P13 + j], hv[j], u0);
#pragma unroll
            for (int j = 3; j < P13; j += 2) u1 = fmaf(c1c.v[dy * P13 + j], hv[j], u1);
            U[hr][64 + hm][dy] = u0 + u1;
        }
        vw[hr][64 + hm] = ws;
    }
    __syncthreads();                        // halo is cross-wave now

    float num = 0.0f;
#pragma unroll
    for (int dy = 0; dy < P13; ++dy) num += U[wv][lane + 12 - dy][dy];
    float den = 0.0f;
#pragma unroll
    for (int d = 0; d < P13; ++d) den += vw[wv][lane + d];
    const int ow = cb + lane;
    if (ow < OUTW)
        outg[((size_t)img * OUTW + a) * OUTW + ow] = num * __builtin_amdgcn_rcpf(den);
}

extern "C" void kernel_launch(void* const* d_in, const int* in_sizes, int n_in,
                              void* d_out, int out_size, void* d_ws, size_t ws_size,
                              hipStream_t stream)
{
    const float* x     = (const float*)d_in[0];
    const float* sigma = (const float*)d_in[1];
    float* out = (float*)d_out;

    // ws: Hg (2*488*512*16 f32 = 31.98 MB) then Wg (2*512*512 f32 = 2 MB)
    float* Hg = (float*)d_ws;
    float* Wg = Hg + (size_t)2 * OUTW * HCOLS * HPITCH;

    dct2net_k2<<<dim3(128, NSEG, 2), 64, 0, stream>>>(x, sigma, Hg, Wg);
    dct2net_k3<<<dim3(8, 122, 2), 256, 0, stream>>>(Hg, Wg, out);
}

// Round 4
// 178.827 us; speedup vs baseline: 1.3232x; 1.3232x over previous
//
#include <hip/hip_runtime.h>
#include <math.h>

// DCT2net, R9: R7 structure + SGPR constant pool + squaring shrink.
//
// R8 post-mortem: 13x-unrolled loop (~38KB) blew the 32KB I$; VGPR 152 and
// 1-wave blocks cut occupancy; FETCH 3.1->8.5MB. Reverted to R7 shape.
//
// R9 theory: v_fma_f32 (VOP3) can't take 32-bit literals; 169 c1 constants
// don't fit SGPRs -> compiler re-materializes ~200 v_mov/step (~35% of busy).
// But c1[r][c] = +-sqrt(2/13)*cos(q*pi/26), q in 0..12 (+1 for k=0 col):
// only 14 distinct magnitudes; signs are free VOP3 neg modifiers. Pin the 14
// in SGPRs (asm "+s"), fold index/sign via constexpr tables -> every
// coefficient FMA is v_fma vD, sC, vX, vD. Keeps R8's wins: squaring-chain
// shrink (1 trans/coeff), pnz = 13 - sum(r), unconditional x loads,
// SALU pointer-increment stores.
//
// K2: per lane-group of 16 (13 kj used), one patch column. Streams rows:
//   hDCT (x via ds_bpermute) -> ring Rv -> vDCT+shrink -> tn, pnzr
//   -> w via 4-step DPP row_ror -> weighted vertical fold ring Hr
//   -> vertical w box-sum (12-ring + running vs) -> retire H row + vs.
// K3: U[c][dy] = sum_j c1[dy][j] H[a][c][j]; out = diag-sum / col-sum of vs.
//
// ws: Hg = 2*488*512*16 f32 (31.98 MB), Wg = 2*512*512 f32 (2 MB).

#define P13    13
#define IMGW   512
#define OUTW   488
#define SEGH   31      // 15*31 + 23 = 488
#define NSEG   16
#define HCOLS  512
#define HPITCH 16

struct C1mat { float v[P13 * P13]; };

// ---- compile-time DCT tables ----
constexpr double kPI = 3.14159265358979323846264338327950288;

constexpr double ccos_pm_pi(double th) {   // Taylor, |th| <= pi
    double term = 1.0, s = 1.0;
    const double th2 = th * th;
    for (int n = 1; n <= 25; ++n) {
        term *= -th2 / (double)((2 * n - 1) * (2 * n));
        s += term;
    }
    return s;
}
constexpr double csqrt(double v) {
    double x = (v > 1.0) ? v : 1.0;
    for (int i = 0; i < 64; ++i) x = 0.5 * (x + v / x);
    return x;
}
constexpr C1mat make_c1() {
    C1mat m{};
    const double s213 = csqrt(2.0 / 13.0);
    const double is2  = 1.0 / csqrt(2.0);
    for (int x = 0; x < P13; ++x)
        for (int k = 0; k < P13; ++k) {
            int mm = ((2 * x + 1) * k) % 52;
            double th = (mm <= 26) ? (mm * kPI / 26.0) : ((mm - 52) * kPI / 26.0);
            double Ci = (k == 0) ? is2 : 1.0;
            m.v[x * P13 + k] = (float)(s213 * Ci * ccos_pm_pi(th));
        }
    return m;
}
__device__ constexpr C1mat c1c = make_c1();

// c1[r][c] = sgn * A[idx]; A[q] = s213*cos(q*pi/26) (q=0..12), A[13] = s213/sqrt(2).
// (r=6, odd c) entries are exactly 0 and are never referenced in k2's split code.
struct CTab { int idx[P13][P13]; bool neg[P13][P13]; float a[14]; };
constexpr CTab make_ctab() {
    CTab t{};
    const double s213 = csqrt(2.0 / 13.0);
    for (int q = 0; q <= 12; ++q) t.a[q] = (float)(s213 * ccos_pm_pi(q * kPI / 26.0));
    t.a[13] = (float)(s213 / csqrt(2.0));
    for (int r = 0; r < P13; ++r)
        for (int c = 0; c < P13; ++c) {
            if (c == 0) { t.idx[r][c] = 13; t.neg[r][c] = false; continue; }
            int m = ((2 * r + 1) * c) % 52;
            int q; bool n;
            if (m <= 13)      { q = m;      n = false; }  // m=13 -> zero coeff (unused)
            else if (m <= 26) { q = 26 - m; n = true;  }
            else if (m <= 39) { q = m - 26; n = true;  }  // m=39 -> zero coeff (unused)
            else              { q = 52 - m; n = false; }
            t.idx[r][c] = q; t.neg[r][c] = n;
        }
    return t;
}
constexpr CTab ctab = make_ctab();

// compile-time-folded signed SGPR constant (r,c constant after unroll)
#define KC(r, c) (ctab.neg[(r)][(c)] ? -As[ctab.idx[(r)][(c)]] : As[ctab.idx[(r)][(c)]])

struct FalseT { static constexpr bool value = false; };
struct TrueT  { static constexpr bool value = true; };

// rotate-reduce add within each 16-lane DPP row: N in {1,2,4,8}
#define ROR16_ADD(v, N)                                                        \
    v += __int_as_float(__builtin_amdgcn_mov_dpp(__float_as_int(v),            \
                                                 0x120 + (N), 0xF, 0xF, true))

// vDCT + shrink. pnzr accumulates r = 1/(1+u^64); pnz = 13 - pnzr.
// Idle lanes (Rv==0): t=0 -> r=1 exactly -> contributes 0.
__device__ __forceinline__ void vdct_shrink(const float (&Rv)[P13], const float (&As)[14],
                                            float i2sq, float (&tn)[P13], float& pnzr)
{
    float Se[6], So[6];
#pragma unroll
    for (int k = 0; k < 6; ++k) { Se[k] = Rv[k] + Rv[12 - k]; So[k] = Rv[k] - Rv[12 - k]; }
#pragma unroll
    for (int i = 0; i < P13; ++i) {
        float t;
        if ((i & 1) == 0) {
            t = KC(6, i) * Rv[6];
#pragma unroll
            for (int k = 0; k < 6; ++k) t = fmaf(KC(k, i), Se[k], t);
        } else {
            t = KC(0, i) * So[0];
#pragma unroll
            for (int k = 1; k < 6; ++k) t = fmaf(KC(k, i), So[k], t);
        }
        // p2 = min((t*inv3s)^2, 1.69) == med3-clamp squared
        float p2 = fminf(t * t * i2sq, 1.69f);
        float p4 = p2 * p2, p8 = p4 * p4, p16 = p8 * p8, p32 = p16 * p16, p64 = p32 * p32;
        float r  = __builtin_amdgcn_rcpf(p64 + 1.0f);
        pnzr += r;
        tn[i] = fmaf(-t, r, t);      // t*nz, nz = 1-r
    }
}

// weighted vertical inverse fold
__device__ __forceinline__ void fold_vert(const float (&tn)[P13], const float (&As)[14],
                                          float w1, float (&H)[P13])
{
#pragma unroll
    for (int dx = 0; dx < 6; ++dx) {
        float E = KC(dx, 0) * tn[0];
#pragma unroll
        for (int i = 2; i < P13; i += 2) E = fmaf(KC(dx, i), tn[i], E);
        float O = KC(dx, 1) * tn[1];
#pragma unroll
        for (int i = 3; i < P13; i += 2) O = fmaf(KC(dx, i), tn[i], O);
        H[dx]      = fmaf(w1, E + O, H[dx]);
        H[12 - dx] = fmaf(w1, E - O, H[12 - dx]);
    }
    float z6 = KC(6, 0) * tn[0];
#pragma unroll
    for (int i = 2; i < P13; i += 2) z6 = fmaf(KC(6, i), tn[i], z6);
    H[6] = fmaf(w1, z6, H[6]);
}

__global__ __launch_bounds__(256) void dct2net_k2(
    const float* __restrict__ xg, const float* __restrict__ sigmag,
    float* __restrict__ Hg, float* __restrict__ Wg)
{
    __shared__ float c1lds[169];
    const int tid = threadIdx.x;
    if (tid < 169) c1lds[tid] = c1c.v[tid];
    __syncthreads();                       // once, for the c1 table only

    const int lane = tid & 63;
    const int wv   = tid >> 6;
    const int g    = lane >> 4;            // col group 0..3
    const int jj   = lane & 15;            // kj (0..12 used)
    const int img  = blockIdx.z;
    const int hs   = blockIdx.y * SEGH;
    const int segrows = (OUTW - hs < SEGH) ? (OUTW - hs) : SEGH;
    const int cbw  = blockIdx.x * 16 + wv * 4;
    const int col  = cbw + g;

    const float inv3s = 1.0f / (3.0f * sigmag[0]);
    const float i2sq  = inv3s * inv3s;
    const float* xin  = xg + (size_t)img * IMGW * IMGW;

    // the 14-constant pool, pinned opaque in SGPRs
    float As[14];
#pragma unroll
    for (int q = 0; q < 14; ++q) As[q] = ctab.a[q];
#pragma unroll
    for (int q = 0; q < 14; ++q) asm("" : "+s"(As[q]));

    // per-lane c1 column for the hDCT (runtime jj -> LDS); 0 for idle lanes
    float c1col[P13];
#pragma unroll
    for (int y = 0; y < P13; ++y)
        c1col[y] = (jj < 13) ? c1lds[y * P13 + jj] : 0.0f;

    float Rv[P13], Hr[P13], wr[12];
#pragma unroll
    for (int k = 0; k < P13; ++k) { Rv[k] = 0.0f; Hr[k] = 0.0f; }
#pragma unroll
    for (int k = 0; k < 12; ++k) wr[k] = 0.0f;
    float vs = 0.0f;

    int xcol = cbw + (lane & 15); xcol = (xcol < IMGW - 1) ? xcol : (IMGW - 1);
    const float* xp    = xin + (size_t)hs * IMGW;
    const float* xlast = xin + (size_t)(IMGW - 1) * IMGW;
    float xv = xp[xcol];                   // all 64 lanes; dup cols coalesce
    xp += IMGW;

    float* Hp = Hg + ((size_t)img * OUTW + hs) * HCOLS * HPITCH;
    float* Wp = Wg + ((size_t)img * IMGW + hs) * IMGW;
    const int voH = col * HPITCH + jj;
    const int voW = col;

    auto step = [&](auto SH, auto RT) {
        float xw[P13];
#pragma unroll
        for (int y = 0; y < P13; ++y)
            xw[y] = __int_as_float(
                __builtin_amdgcn_ds_bpermute(4 * (g + y), __float_as_int(xv)));
        { const float* xq = (xp < xlast) ? xp : xlast; xv = xq[xcol]; xp += IMGW; }
        float a0 = c1col[0] * xw[0], a1 = c1col[1] * xw[1];
#pragma unroll
        for (int y = 2; y < P13; y += 2) a0 = fmaf(c1col[y], xw[y], a0);
#pragma unroll
        for (int y = 3; y < P13; y += 2) a1 = fmaf(c1col[y], xw[y], a1);
#pragma unroll
        for (int q = 0; q < P13 - 1; ++q) Rv[q] = Rv[q + 1];
        Rv[P13 - 1] = a0 + a1;

        if constexpr (decltype(SH)::value) {
            float tn[P13]; float pnzr = 0.0f;
            vdct_shrink(Rv, As, i2sq, tn, pnzr);
            float pnz = 13.0f - pnzr;      // idle lanes: exactly 0
            ROR16_ADD(pnz, 1); ROR16_ADD(pnz, 2); ROR16_ADD(pnz, 4); ROR16_ADD(pnz, 8);
            const float w = __builtin_amdgcn_rcpf(1.0f + pnz);
            vs += w;
            fold_vert(tn, As, w, Hr);
            if constexpr (decltype(RT)::value) {
                Hp[voH] = Hr[0];
                Hp += HCOLS * HPITCH;
                if (jj == 0) Wp[voW] = vs;
                Wp += IMGW;
                vs -= wr[0];               // drop w(a) BEFORE the ring shift
            }
#pragma unroll
            for (int q = 0; q < 11; ++q) wr[q] = wr[q + 1];
            wr[11] = w;
#pragma unroll
            for (int q = 0; q < P13 - 1; ++q) Hr[q] = Hr[q + 1];
            Hr[P13 - 1] = 0.0f;
        }
    };

#pragma unroll 4
    for (int k = 0; k < 12; ++k) step(FalseT{}, FalseT{});    // fill Rv
#pragma unroll 4
    for (int k = 0; k < 12; ++k) step(TrueT{}, FalseT{});     // fill Hr/wr/vs
    const int kend = segrows;
#pragma unroll 4
    for (int k = 0; k < kend; ++k) step(TrueT{}, TrueT{});    // steady: retire
}

__global__ __launch_bounds__(256) void dct2net_k3(
    const float* __restrict__ Hg, const float* __restrict__ Wg,
    float* __restrict__ outg)
{
    __shared__ float U[4][76][14];   // stride 14: 2-way bank alias only (free)
    __shared__ float vw[4][80];
    const int tid  = threadIdx.x;
    const int lane = tid & 63;
    const int wv   = tid >> 6;
    const int img  = blockIdx.z;
    const int a0   = blockIdx.y * 4;
    const int a    = a0 + wv;               // out row (<= 487)
    const int cb   = blockIdx.x * 64;       // out col base

    // ---- issue all loads up front (main + halo) ----
    int c = cb + lane; c = (c < 499) ? c : 499;
    const float* hp = &Hg[(((size_t)img * OUTW + a) * HCOLS + c) * HPITCH];
    float4 m0 = *(const float4*)hp;
    float4 m1 = *(const float4*)(hp + 4);
    float4 m2 = *(const float4*)(hp + 8);
    float  m3 = hp[12];
    float  wm = Wg[((size_t)img * IMGW + a) * IMGW + c];

    const bool halo = (tid < 48);           // wave 0: 4 rows x 12 halo cols
    const int  hr = tid / 12;
    const int  hm = tid - hr * 12;
    float4 s0 = {0,0,0,0}, s1 = {0,0,0,0}, s2 = {0,0,0,0};
    float  s3 = 0.0f, ws = 0.0f;
    if (halo) {
        const int ah = a0 + hr;
        int c2 = cb + 64 + hm; c2 = (c2 < 499) ? c2 : 499;
        const float* hq = &Hg[(((size_t)img * OUTW + ah) * HCOLS + c2) * HPITCH];
        s0 = *(const float4*)hq;
        s1 = *(const float4*)(hq + 4);
        s2 = *(const float4*)(hq + 8);
        s3 = hq[12];
        ws = Wg[((size_t)img * IMGW + ah) * IMGW + c2];
    }

    // ---- main build ----
    {
        float hv[P13] = {m0.x,m0.y,m0.z,m0.w, m1.x,m1.y,m1.z,m1.w,
                         m2.x,m2.y,m2.z,m2.w, m3};
#pragma unroll
        for (int dy = 0; dy < P13; ++dy) {
            float u0 = c1c.v[dy * P13 + 0] * hv[0];
            float u1 = c1c.v[dy * P13 + 1] * hv[1];
#pragma unroll
            for (int j = 2; j < P13; j += 2) u0 = fmaf(c1c.v[dy * P13 + j], hv[j], u0);
#pragma unroll
            for (int j = 3; j < P13; j += 2) u1 = fmaf(c1c.v[dy * P13 + j], hv[j], u1);
            U[wv][lane][dy] = u0 + u1;
        }
        vw[wv][lane] = wm;
    }
    // ---- halo build ----
    if (halo) {
        float hv[P13] = {s0.x,s0.y,s0.z,s0.w, s1.x,s1.y,s1.z,s1.w,
                         s2.x,s2.y,s2.z,s2.w, s3};
#pragma unroll
        for (int dy = 0; dy < P13; ++dy) {
            float u0 = c1c.v[dy * P13 + 0] * hv[0];
            float u1 = c1c.v[dy * P13 + 1] * hv[1];
#pragma unroll
            for (int j = 2; j < P13; j += 2) u0 = fmaf(c1c.v[dy * P13 + j], hv[j], u0);
#pragma unroll
            for (int j = 3; j < P13; j += 2) u1 = fmaf(c1c.v[dy * P13 + j], hv[j], u1);
            U[hr][64 + hm][dy] = u0 + u1;
        }
        vw[hr][64 + hm] = ws;
    }
    __syncthreads();

    float num = 0.0f;
#pragma unroll
    for (int dy = 0; dy < P13; ++dy) num += U[wv][lane + 12 - dy][dy];
    float den = 0.0f;
#pragma unroll
    for (int d = 0; d < P13; ++d) den += vw[wv][lane + d];
    const int ow = cb + lane;
    if (ow < OUTW)
        outg[((size_t)img * OUTW + a) * OUTW + ow] = num * __builtin_amdgcn_rcpf(den);
}

extern "C" void kernel_launch(void* const* d_in, const int* in_sizes, int n_in,
                              void* d_out, int out_size, void* d_ws, size_t ws_size,
                              hipStream_t stream)
{
    const float* x     = (const float*)d_in[0];
    const float* sigma = (const float*)d_in[1];
    float* out = (float*)d_out;

    // ws: Hg (2*488*512*16 f32 = 31.98 MB) then Wg (2*512*512 f32 = 2 MB)
    float* Hg = (float*)d_ws;
    float* Wg = Hg + (size_t)2 * OUTW * HCOLS * HPITCH;

    dct2net_k2<<<dim3(32, NSEG, 2), 256, 0, stream>>>(x, sigma, Hg, Wg);
    dct2net_k3<<<dim3(8, 122, 2), 256, 0, stream>>>(Hg, Wg, out);
}